// Round 5
// baseline (468.440 us; speedup 1.0000x reference)
//
#include <hip/hip_runtime.h>
#include <hip/hip_bf16.h>
#include <stdint.h>

typedef float f32x4 __attribute__((ext_vector_type(4)));
typedef short bf16x8 __attribute__((ext_vector_type(8)));

#define NPATCH 6272      // 8*28*28
#define CTOT   384
#define MBANK  30000
#define MROWS  6400      // NPATCH padded to 25*256
#define NCOLS  30208     // MBANK padded to 118*256
#define NKT    6         // 384/64 K-tiles

#define NPB    (MROWS / 4)            // prep blocks for patches (1600)
#define NBB    (NCOLS / 4)            // prep blocks for bank (7552)

// ---------------------------------------------------------------- fused prep
// blocks [0, NPB): patch rows (bilinear+concat+bf16+x_sq+nn_d2 init)
// blocks [NPB, NPB+NBB): bank rows (bf16 cast + m_sq)
__global__ __launch_bounds__(256) void prep_kernel(
    const float* __restrict__ f2, const float* __restrict__ f3,
    const float* __restrict__ mb,
    __hip_bfloat16* __restrict__ A, __hip_bfloat16* __restrict__ Bb,
    float* __restrict__ x_sq, float* __restrict__ m_sq,
    float* __restrict__ nn_d2)
{
  const int lane = threadIdx.x & 63;
  const int sub  = threadIdx.x >> 6;

  if (blockIdx.x < NPB) {
    const int n = blockIdx.x * 4 + sub;
    if (n >= NPATCH) {       // zero-fill pad rows
      #pragma unroll
      for (int j = 0; j < 6; ++j) A[(size_t)n * CTOT + j * 64 + lane] = __float2bfloat16(0.f);
      return;
    }
    const int b = n / 784;
    const int hw = n - b * 784;
    const int h = hw / 28;
    const int w = hw - h * 28;

    // align_corners=False bilinear, scale 2 (edge-clamped == jax renormalized)
    int h0, h1, w0i, w1i; float wh0, wh1, ww0, ww1;
    if (h & 1) { int k = h >> 1; h0 = k; h1 = (k + 1 < 14) ? k + 1 : 13; wh0 = 0.75f; wh1 = 0.25f; }
    else       { int k = h >> 1; h0 = (k > 0) ? k - 1 : 0; h1 = k;       wh0 = 0.25f; wh1 = 0.75f; }
    if (w & 1) { int k = w >> 1; w0i = k; w1i = (k + 1 < 14) ? k + 1 : 13; ww0 = 0.75f; ww1 = 0.25f; }
    else       { int k = w >> 1; w0i = (k > 0) ? k - 1 : 0; w1i = k;       ww0 = 0.25f; ww1 = 0.75f; }

    float ssum = 0.f;
    #pragma unroll
    for (int j = 0; j < 6; ++j) {
      const int c = j * 64 + lane;
      float v;
      if (j < 2) {
        v = f2[(((size_t)b * 128 + c) * 28 + h) * 28 + w];
      } else {
        const int c3 = c - 128;
        const float* p = f3 + ((size_t)b * 256 + c3) * 196;
        v = wh0 * (ww0 * p[h0 * 14 + w0i] + ww1 * p[h0 * 14 + w1i]) +
            wh1 * (ww0 * p[h1 * 14 + w0i] + ww1 * p[h1 * 14 + w1i]);
      }
      A[(size_t)n * CTOT + c] = __float2bfloat16(v);
      ssum += v * v;
    }
    #pragma unroll
    for (int off = 32; off; off >>= 1) ssum += __shfl_xor(ssum, off);
    if (lane == 0) { x_sq[n] = ssum; nn_d2[n] = __uint_as_float(0x7f800000u); }
  } else {
    const int m = (blockIdx.x - NPB) * 4 + sub;
    if (m < MBANK) {
      float ssum = 0.f;
      #pragma unroll
      for (int j = 0; j < 3; ++j) {
        const int c = j * 128 + lane * 2;
        const float2 v = *(const float2*)&mb[(size_t)m * CTOT + c];
        short2 o;
        o.x = (short)__bfloat16_as_ushort(__float2bfloat16(v.x));
        o.y = (short)__bfloat16_as_ushort(__float2bfloat16(v.y));
        *(short2*)&Bb[(size_t)m * CTOT + c] = o;
        ssum += v.x * v.x + v.y * v.y;
      }
      #pragma unroll
      for (int off = 32; off; off >>= 1) ssum += __shfl_xor(ssum, off);
      if (lane == 0) m_sq[m] = ssum;
    } else {
      #pragma unroll
      for (int j = 0; j < 6; ++j) Bb[(size_t)m * CTOT + j * 64 + lane] = __float2bfloat16(0.f);
      if (lane == 0) m_sq[m] = __uint_as_float(0x7f800000u);
    }
  }
}

// ---------------------------------------------------------------- GEMM + row-min
__device__ __forceinline__ void gl_lds16(const void* g, void* l) {
  __builtin_amdgcn_global_load_lds(
      (const __attribute__((address_space(1))) uint32_t*)g,
      (__attribute__((address_space(3))) uint32_t*)l, 16, 0, 0);
}

// 256x256 tile, BK=64, 8 waves (2Mx4N; 128x64/wave, 8x4 frags of 16x16x32).
// m201-style 4-phase-per-K-tile schedule: each phase {ds_read subtile ||
// 2 gl_lds stage issues -> s_barrier -> lgkmcnt(0) -> setprio(1) 16 MFMA
// setprio(0) -> s_barrier}. Tile t+1 staged across tile t's 4 phases into the
// buffer freed at end of tile t-1; boundary vmcnt(0) therefore waits on loads
// issued ~4 phases earlier (nearly free). 16B-chunk XOR swizzle (ch ^= row&7)
// via inverse-swizzled GLOBAL source + swizzled ds_read addr (linear LDS dest).
__global__ __launch_bounds__(512, 2) void gemm_min_kernel(
    const __hip_bfloat16* __restrict__ A, const __hip_bfloat16* __restrict__ B,
    const float* __restrict__ x_sq, const float* __restrict__ m_sq,
    float* __restrict__ nn_d2)
{
  __shared__ __align__(16) short As[2][256 * 64];
  __shared__ __align__(16) short Bs[2][256 * 64];
  const int tid  = threadIdx.x;
  const int lane = tid & 63;
  const int wid  = tid >> 6;
  const int wr = wid >> 2;          // 0..1  (M half)
  const int wc = wid & 3;           // 0..3  (N quarter)
  const int row0 = blockIdx.y * 256;
  const int col0 = blockIdx.x * 256;

  f32x4 acc[8][4];
  #pragma unroll
  for (int i = 0; i < 8; ++i)
    #pragma unroll
    for (int j = 0; j < 4; ++j) acc[i][j] = (f32x4){0.f, 0.f, 0.f, 0.f};

  // stage pair j (j=0..3) of K-tile kt into buffer buf: one A + one B gl_lds.
  auto stage_pair = [&](int kt, int buf, int j) {
    const int k0 = kt * 64;
    const int cb = j * 512 + wid * 64;      // wave-uniform chunk base
    const int c  = cb + lane;
    const int r  = c >> 3;                  // tile row 0..255
    const int ch = (c & 7) ^ (r & 7);       // swizzled 16B chunk in row
    gl_lds16(A + (size_t)(row0 + r) * CTOT + k0 + ch * 8, &As[buf][cb * 8]);
    gl_lds16(B + (size_t)(col0 + r) * CTOT + k0 + ch * 8, &Bs[buf][cb * 8]);
  };

  #pragma unroll
  for (int j = 0; j < 4; ++j) stage_pair(0, 0, j);
  #pragma unroll
  for (int j = 0; j < 4; ++j) stage_pair(1, 1, j);
  asm volatile("s_waitcnt vmcnt(8)" ::: "memory");   // tile 0 landed
  __builtin_amdgcn_s_barrier();

  const int sw = lane & 7;            // row&7 of every frag row this lane reads
  const int rA = wr * 128 + (lane & 15);
  const int rB = wc * 64 + (lane & 15);
  const int kq = lane >> 4;           // k-quarter 0..3
  const int ch0 = (kq ^ sw) << 4;     // kk=0 swizzled byte chunk
  const int ch1 = ((4 + kq) ^ sw) << 4;

  #pragma unroll
  for (int t = 0; t < NKT; ++t) {
    const int cur = t & 1;
    const char* lA = (const char*)As[cur];
    const char* lB = (const char*)Bs[cur];
    const bool st = (t >= 1) && (t + 1 < NKT);
    bf16x8 a0[8], b0[4], a1[8], b1[4];

    // ---- phase 1: b0 + a0[0..3] reads, stage pair 0, MFMA (kk0, mi 0-3)
    #pragma unroll
    for (int ni = 0; ni < 4; ++ni) b0[ni] = *(const bf16x8*)(lB + (rB + ni * 16) * 128 + ch0);
    #pragma unroll
    for (int mi = 0; mi < 4; ++mi) a0[mi] = *(const bf16x8*)(lA + (rA + mi * 16) * 128 + ch0);
    if (st) stage_pair(t + 1, cur ^ 1, 0);
    __builtin_amdgcn_s_barrier();
    asm volatile("s_waitcnt lgkmcnt(0)" ::: "memory");
    __builtin_amdgcn_s_setprio(1);
    #pragma unroll
    for (int mi = 0; mi < 4; ++mi)
      #pragma unroll
      for (int ni = 0; ni < 4; ++ni)
        acc[mi][ni] = __builtin_amdgcn_mfma_f32_16x16x32_bf16(a0[mi], b0[ni], acc[mi][ni], 0, 0, 0);
    __builtin_amdgcn_s_setprio(0);
    __builtin_amdgcn_s_barrier();

    // ---- phase 2: a0[4..7] reads, stage pair 1, MFMA (kk0, mi 4-7)
    #pragma unroll
    for (int mi = 4; mi < 8; ++mi) a0[mi] = *(const bf16x8*)(lA + (rA + mi * 16) * 128 + ch0);
    if (st) stage_pair(t + 1, cur ^ 1, 1);
    __builtin_amdgcn_s_barrier();
    asm volatile("s_waitcnt lgkmcnt(0)" ::: "memory");
    __builtin_amdgcn_s_setprio(1);
    #pragma unroll
    for (int mi = 4; mi < 8; ++mi)
      #pragma unroll
      for (int ni = 0; ni < 4; ++ni)
        acc[mi][ni] = __builtin_amdgcn_mfma_f32_16x16x32_bf16(a0[mi], b0[ni], acc[mi][ni], 0, 0, 0);
    __builtin_amdgcn_s_setprio(0);
    __builtin_amdgcn_s_barrier();

    // ---- phase 3: b1 + a1[0..3] reads, stage pair 2, MFMA (kk1, mi 0-3)
    #pragma unroll
    for (int ni = 0; ni < 4; ++ni) b1[ni] = *(const bf16x8*)(lB + (rB + ni * 16) * 128 + ch1);
    #pragma unroll
    for (int mi = 0; mi < 4; ++mi) a1[mi] = *(const bf16x8*)(lA + (rA + mi * 16) * 128 + ch1);
    if (st) stage_pair(t + 1, cur ^ 1, 2);
    __builtin_amdgcn_s_barrier();
    asm volatile("s_waitcnt lgkmcnt(0)" ::: "memory");
    __builtin_amdgcn_s_setprio(1);
    #pragma unroll
    for (int mi = 0; mi < 4; ++mi)
      #pragma unroll
      for (int ni = 0; ni < 4; ++ni)
        acc[mi][ni] = __builtin_amdgcn_mfma_f32_16x16x32_bf16(a1[mi], b1[ni], acc[mi][ni], 0, 0, 0);
    __builtin_amdgcn_s_setprio(0);
    __builtin_amdgcn_s_barrier();

    // ---- phase 4: a1[4..7] reads, stage pair 3, MFMA (kk1, mi 4-7), boundary
    #pragma unroll
    for (int mi = 4; mi < 8; ++mi) a1[mi] = *(const bf16x8*)(lA + (rA + mi * 16) * 128 + ch1);
    if (st) stage_pair(t + 1, cur ^ 1, 3);
    __builtin_amdgcn_s_barrier();
    asm volatile("s_waitcnt lgkmcnt(0)" ::: "memory");
    __builtin_amdgcn_s_setprio(1);
    #pragma unroll
    for (int mi = 4; mi < 8; ++mi)
      #pragma unroll
      for (int ni = 0; ni < 4; ++ni)
        acc[mi][ni] = __builtin_amdgcn_mfma_f32_16x16x32_bf16(a1[mi], b1[ni], acc[mi][ni], 0, 0, 0);
    __builtin_amdgcn_s_setprio(0);
    if (t + 1 < NKT)
      asm volatile("s_waitcnt vmcnt(0)" ::: "memory");  // tile t+1 landed (issued >=4 phases ago)
    __builtin_amdgcn_s_barrier();
  }

  // epilogue: C/D frag layout col=lane&15, row=(lane>>4)*4+reg
  float msq[4];
  #pragma unroll
  for (int ni = 0; ni < 4; ++ni) msq[ni] = m_sq[col0 + wc * 64 + ni * 16 + (lane & 15)];

  #pragma unroll
  for (int mi = 0; mi < 8; ++mi) {
    #pragma unroll
    for (int r = 0; r < 4; ++r) {
      float t = msq[0] - 2.f * acc[mi][0][r];
      #pragma unroll
      for (int ni = 1; ni < 4; ++ni) t = fminf(t, msq[ni] - 2.f * acc[mi][ni][r]);
      t = fminf(t, __shfl_xor(t, 1));
      t = fminf(t, __shfl_xor(t, 2));
      t = fminf(t, __shfl_xor(t, 4));
      t = fminf(t, __shfl_xor(t, 8));
      if ((lane & 15) == 0) {
        const int rg = row0 + wr * 128 + mi * 16 + ((lane >> 4) << 2) + r;
        if (rg < NPATCH) {
          const float v = fmaxf(t + x_sq[rg], 0.f);
          atomicMin((unsigned int*)&nn_d2[rg], __float_as_uint(v));
        }
      }
    }
  }
}

// ---------------------------------------------------------------- finalize
__global__ __launch_bounds__(256) void finalize_kernel(
    const float* __restrict__ nn_d2, float* __restrict__ out)
{
  const int b = blockIdx.x;
  const int tid = threadIdx.x;
  __shared__ float red[4];
  float lmax = 0.f;
  for (int i = tid; i < 784; i += 256) {
    const float d2 = nn_d2[b * 784 + i];
    const float s = sqrtf(fmaxf(d2, 1e-12f));
    out[b * 784 + i] = s;
    lmax = fmaxf(lmax, s);
  }
  #pragma unroll
  for (int off = 32; off; off >>= 1) lmax = fmaxf(lmax, __shfl_xor(lmax, off));
  if ((tid & 63) == 0) red[tid >> 6] = lmax;
  __syncthreads();
  if (tid == 0)
    out[6272 + b] = fmaxf(fmaxf(red[0], red[1]), fmaxf(red[2], red[3]));
}

// ---------------------------------------------------------------- launch
extern "C" void kernel_launch(void* const* d_in, const int* in_sizes, int n_in,
                              void* d_out, int out_size, void* d_ws, size_t ws_size,
                              hipStream_t stream)
{
  const float* f2 = (const float*)d_in[0];   // [8,128,28,28]
  const float* f3 = (const float*)d_in[1];   // [8,256,14,14]
  const float* mb = (const float*)d_in[2];   // [30000,384]
  float* out = (float*)d_out;                // 6272 patch scores + 8 img scores

  // workspace layout (16B-aligned offsets), total ~28.3 MB
  uint8_t* ws = (uint8_t*)d_ws;
  __hip_bfloat16* A  = (__hip_bfloat16*)(ws);              // 6400*384*2  = 4,915,200
  __hip_bfloat16* Bb = (__hip_bfloat16*)(ws + 4915200);    // 30208*384*2 = 23,199,744
  float* x_sq  = (float*)(ws + 28114944);                  // 6400*4
  float* m_sq  = (float*)(ws + 28140544);                  // 30208*4
  float* nn_d2 = (float*)(ws + 28261376);                  // 6272*4

  hipLaunchKernelGGL(prep_kernel, dim3(NPB + NBB), dim3(256), 0, stream,
                     f2, f3, mb, A, Bb, x_sq, m_sq, nn_d2);
  hipLaunchKernelGGL(gemm_min_kernel, dim3(NCOLS / 256, MROWS / 256), dim3(512), 0, stream,
                     A, Bb, x_sq, m_sq, nn_d2);
  hipLaunchKernelGGL(finalize_kernel, dim3(8), dim3(256), 0, stream, nn_d2, out);
}

// Round 9
// 441.831 us; speedup vs baseline: 1.0602x; 1.0602x over previous
//
#include <hip/hip_runtime.h>
#include <hip/hip_bf16.h>
#include <stdint.h>

typedef float f32x4 __attribute__((ext_vector_type(4)));
typedef short bf16x8 __attribute__((ext_vector_type(8)));

#define NPATCH 6272      // 8*28*28
#define CTOT   384
#define MBANK  30000
#define MROWS  6400      // NPATCH padded to 25*256
#define NCOLS  30720     // MBANK padded to 120*256
#define NCT    120       // col tiles
#define W      12        // col tiles walked per block
#define NCG    10        // col groups = NCT/W

// prep block ranges
#define PF2B   16                 // 8 imgs * 2 csegs of 64
#define PF3B   32                 // 8 imgs * 4 csegs of 64
#define PBANKB (NCOLS / 4)        // 7680
#define NPREP  (PF2B + PF3B + PBANKB)

// ---------------------------------------------------------------- fused prep
// [0,16):  f2 transpose  (b, cseg64) -> A cols 0..127, coalesced both sides
// [16,48): f3 bilinear+transpose (b, cseg64) -> A cols 128..383
// [48,..): memory bank bf16 cast + m_sq (pad rows zero / +inf)
__global__ __launch_bounds__(256) void prep_kernel(
    const float* __restrict__ f2, const float* __restrict__ f3,
    const float* __restrict__ mb,
    __hip_bfloat16* __restrict__ A, __hip_bfloat16* __restrict__ Bb,
    float* __restrict__ m_sq)
{
  __shared__ float tile[64 * 197];   // f2 path uses [64][65], f3 uses [64][197]
  const int t = threadIdx.x;
  const int lane = t & 63;
  const int grp  = t >> 6;

  if (blockIdx.x < PF2B) {
    // ---- f2: [b][c][28][28] -> A[b*784+hw][c], c in [c0, c0+64)
    const int b  = blockIdx.x >> 1;
    const int c0 = (blockIdx.x & 1) * 64;
    const float* src = f2 + ((size_t)b * 128 + c0) * 784;
    __hip_bfloat16* dst = A + (size_t)b * 784 * CTOT + c0;
    for (int hw0 = 0; hw0 < 784; hw0 += 64) {
      const int nhw = (784 - hw0 < 64) ? (784 - hw0) : 64;
      __syncthreads();
      #pragma unroll
      for (int k = 0; k < 16; ++k) {     // read: lanes -> hw (coalesced)
        const int c = grp * 16 + k;
        if (lane < nhw) tile[c * 65 + lane] = src[(size_t)c * 784 + hw0 + lane];
      }
      __syncthreads();
      #pragma unroll
      for (int k = 0; k < 16; ++k) {     // write: lanes -> c (coalesced)
        const int r = grp * 16 + k;
        if (r < nhw) dst[(size_t)(hw0 + r) * CTOT + lane] = __float2bfloat16(tile[lane * 65 + r]);
      }
    }
  } else if (blockIdx.x < PF2B + PF3B) {
    // ---- f3: stage whole [64 c][196] plane in LDS, bilinear, write transposed
    const int blk = blockIdx.x - PF2B;
    const int b  = blk >> 2;
    const int c0 = (blk & 3) * 64;
    const float* src = f3 + ((size_t)b * 256 + c0) * 196;
    for (int idx = t; idx < 64 * 196; idx += 256) {
      const int c = idx / 196, p = idx - c * 196;
      tile[c * 197 + p] = src[(size_t)c * 196 + p];
    }
    __syncthreads();
    __hip_bfloat16* dst = A + (size_t)b * 784 * CTOT + 128 + c0;
    for (int hw0 = 0; hw0 < 784; hw0 += 64) {
      #pragma unroll
      for (int k = 0; k < 16; ++k) {
        const int r = grp * 16 + k;
        const int hw = hw0 + r;
        if (hw < 784) {
          const int h = hw / 28, w = hw - h * 28;
          int h0, h1, w0i, w1i; float wh0, wh1, ww0, ww1;
          if (h & 1) { int q = h >> 1; h0 = q; h1 = (q + 1 < 14) ? q + 1 : 13; wh0 = 0.75f; wh1 = 0.25f; }
          else       { int q = h >> 1; h0 = (q > 0) ? q - 1 : 0; h1 = q;       wh0 = 0.25f; wh1 = 0.75f; }
          if (w & 1) { int q = w >> 1; w0i = q; w1i = (q + 1 < 14) ? q + 1 : 13; ww0 = 0.75f; ww1 = 0.25f; }
          else       { int q = w >> 1; w0i = (q > 0) ? q - 1 : 0; w1i = q;       ww0 = 0.25f; ww1 = 0.75f; }
          const float* tl = &tile[lane * 197];
          const float v = wh0 * (ww0 * tl[h0 * 14 + w0i] + ww1 * tl[h0 * 14 + w1i]) +
                          wh1 * (ww0 * tl[h1 * 14 + w0i] + ww1 * tl[h1 * 14 + w1i]);
          dst[(size_t)hw * CTOT + lane] = __float2bfloat16(v);   // lanes -> c, coalesced
        }
      }
    }
  } else {
    // ---- memory bank
    const int m = (blockIdx.x - PF2B - PF3B) * 4 + grp;
    if (m < MBANK) {
      float ssum = 0.f;
      #pragma unroll
      for (int j = 0; j < 3; ++j) {
        const int c = j * 128 + lane * 2;
        const float2 v = *(const float2*)&mb[(size_t)m * CTOT + c];
        short2 o;
        o.x = (short)__bfloat16_as_ushort(__float2bfloat16(v.x));
        o.y = (short)__bfloat16_as_ushort(__float2bfloat16(v.y));
        *(short2*)&Bb[(size_t)m * CTOT + c] = o;
        ssum += v.x * v.x + v.y * v.y;
      }
      #pragma unroll
      for (int off = 32; off; off >>= 1) ssum += __shfl_xor(ssum, off);
      if (lane == 0) m_sq[m] = ssum;
    } else {
      #pragma unroll
      for (int j = 0; j < 6; ++j) Bb[(size_t)m * CTOT + j * 64 + lane] = __float2bfloat16(0.f);
      if (lane == 0) m_sq[m] = __uint_as_float(0x7f800000u);   // +inf: pad col never the min
    }
  }
}

// ---------------------------------------------------------------- GEMM + row-min
__device__ __forceinline__ void gl_lds16(const void* g, void* l) {
  __builtin_amdgcn_global_load_lds(
      (const __attribute__((address_space(1))) uint32_t*)g,
      (__attribute__((address_space(3))) uint32_t*)l, 16, 0, 0);
}

// Persistent col-walk: each block owns 256 rows and walks W=12 col-tiles of
// 256, fusing (col,K) into one 72-deep double-buffered 4-phase pipeline.
// Per col-tile epilogue: per-wave 64-col min -> redm[wc][row] in LDS ->
// __syncthreads -> cross-wave min over the 4 wc slices (the R8 bug was plain
// stores racing across wc) folded into a per-thread running min; ONE partial
// store per block at the last col-tile. x_sq deferred to finalize.
__global__ __launch_bounds__(512, 2) void gemm_min_kernel(
    const __hip_bfloat16* __restrict__ A, const __hip_bfloat16* __restrict__ B,
    const float* __restrict__ m_sq, float* __restrict__ partial)
{
  __shared__ __align__(16) short As[2][256 * 64];
  __shared__ __align__(16) short Bs[2][256 * 64];
  __shared__ float redm[4][256];    // [wc][row-in-tile]
  const int tid  = threadIdx.x;
  const int lane = tid & 63;
  const int wid  = tid >> 6;
  const int wr = wid >> 2;          // 0..1  (M half)
  const int wc = wid & 3;           // 0..3  (N quarter)
  const int row0 = blockIdx.y * 256;
  const int ct0  = blockIdx.x * W;  // first col-tile of this block

  f32x4 acc[8][4];
  #pragma unroll
  for (int i = 0; i < 8; ++i)
    #pragma unroll
    for (int j = 0; j < 4; ++j) acc[i][j] = (f32x4){0.f, 0.f, 0.f, 0.f};

  // stage pair j of (col-tile c2, K-tile kt2) into buffer buf
  auto stage_pair = [&](int c2, int kt2, int buf, int j) {
    const int k0 = kt2 * 64;
    const int cb = j * 512 + wid * 64;      // wave-uniform chunk base
    const int cc = cb + lane;
    const int r  = cc >> 3;                 // tile row 0..255
    const int ch = (cc & 7) ^ (r & 7);      // swizzled 16B chunk in row
    gl_lds16(A + (size_t)(row0 + r) * CTOT + k0 + ch * 8, &As[buf][cb * 8]);
    gl_lds16(B + ((size_t)(ct0 + c2) * 256 + r) * CTOT + k0 + ch * 8, &Bs[buf][cb * 8]);
  };

  #pragma unroll
  for (int j = 0; j < 4; ++j) stage_pair(0, 0, 0, j);
  #pragma unroll
  for (int j = 0; j < 4; ++j) stage_pair(0, 1, 1, j);
  asm volatile("s_waitcnt vmcnt(8)" ::: "memory");   // (c0,k0) landed
  __builtin_amdgcn_s_barrier();

  const int sw = lane & 7;
  const int rA = wr * 128 + (lane & 15);
  const int rB = wc * 64 + (lane & 15);
  const int kq = lane >> 4;
  const int ch0 = (kq ^ sw) << 4;
  const int ch1 = ((4 + kq) ^ sw) << 4;

  float msq[4];
  float runmin = __uint_as_float(0x7f800000u);   // running min across col-tiles

  for (int c = 0; c < W; ++c) {
    #pragma unroll
    for (int kt = 0; kt < 6; ++kt) {
      const int cur = kt & 1;                 // i = c*6+kt; 6c even -> parity = kt&1
      const char* lA = (const char*)As[cur];
      const char* lB = (const char*)Bs[cur];
      const int kt2 = (kt == 5) ? 0 : kt + 1; // next (c2,kt2) staged this iter
      const int c2  = (kt == 5) ? c + 1 : c;
      const bool st = !(c == 0 && kt == 0) && !(c == W - 1 && kt == 5);
      bf16x8 a0[8], b0[4], a1[8], b1[4];

      // ---- phase 1: b0 + a0[0..3] reads, stage pair 0, MFMA (kk0, mi 0-3)
      #pragma unroll
      for (int ni = 0; ni < 4; ++ni) b0[ni] = *(const bf16x8*)(lB + (rB + ni * 16) * 128 + ch0);
      #pragma unroll
      for (int mi = 0; mi < 4; ++mi) a0[mi] = *(const bf16x8*)(lA + (rA + mi * 16) * 128 + ch0);
      if (kt == 0) {            // m_sq for this col-tile (consumed at kt==5)
        const int colb = (ct0 + c) * 256 + wc * 64 + (lane & 15);
        #pragma unroll
        for (int ni = 0; ni < 4; ++ni) msq[ni] = m_sq[colb + ni * 16];
      }
      if (st) stage_pair(c2, kt2, cur ^ 1, 0);
      __builtin_amdgcn_s_barrier();
      asm volatile("s_waitcnt lgkmcnt(0)" ::: "memory");
      __builtin_amdgcn_s_setprio(1);
      #pragma unroll
      for (int mi = 0; mi < 4; ++mi)
        #pragma unroll
        for (int ni = 0; ni < 4; ++ni)
          acc[mi][ni] = __builtin_amdgcn_mfma_f32_16x16x32_bf16(a0[mi], b0[ni], acc[mi][ni], 0, 0, 0);
      __builtin_amdgcn_s_setprio(0);
      __builtin_amdgcn_s_barrier();

      // ---- phase 2: a0[4..7] reads, stage pair 1, MFMA (kk0, mi 4-7)
      #pragma unroll
      for (int mi = 4; mi < 8; ++mi) a0[mi] = *(const bf16x8*)(lA + (rA + mi * 16) * 128 + ch0);
      if (st) stage_pair(c2, kt2, cur ^ 1, 1);
      __builtin_amdgcn_s_barrier();
      asm volatile("s_waitcnt lgkmcnt(0)" ::: "memory");
      __builtin_amdgcn_s_setprio(1);
      #pragma unroll
      for (int mi = 4; mi < 8; ++mi)
        #pragma unroll
        for (int ni = 0; ni < 4; ++ni)
          acc[mi][ni] = __builtin_amdgcn_mfma_f32_16x16x32_bf16(a0[mi], b0[ni], acc[mi][ni], 0, 0, 0);
      __builtin_amdgcn_s_setprio(0);
      __builtin_amdgcn_s_barrier();

      // ---- phase 3: b1 + a1[0..3] reads, stage pair 2, MFMA (kk1, mi 0-3)
      #pragma unroll
      for (int ni = 0; ni < 4; ++ni) b1[ni] = *(const bf16x8*)(lB + (rB + ni * 16) * 128 + ch1);
      #pragma unroll
      for (int mi = 0; mi < 4; ++mi) a1[mi] = *(const bf16x8*)(lA + (rA + mi * 16) * 128 + ch1);
      if (st) stage_pair(c2, kt2, cur ^ 1, 2);
      __builtin_amdgcn_s_barrier();
      asm volatile("s_waitcnt lgkmcnt(0)" ::: "memory");
      __builtin_amdgcn_s_setprio(1);
      #pragma unroll
      for (int mi = 0; mi < 4; ++mi)
        #pragma unroll
        for (int ni = 0; ni < 4; ++ni)
          acc[mi][ni] = __builtin_amdgcn_mfma_f32_16x16x32_bf16(a1[mi], b1[ni], acc[mi][ni], 0, 0, 0);
      __builtin_amdgcn_s_setprio(0);
      __builtin_amdgcn_s_barrier();

      // ---- phase 4: a1[4..7] reads, stage pair 3, MFMA (kk1, mi 4-7)
      #pragma unroll
      for (int mi = 4; mi < 8; ++mi) a1[mi] = *(const bf16x8*)(lA + (rA + mi * 16) * 128 + ch1);
      if (st) stage_pair(c2, kt2, cur ^ 1, 3);
      __builtin_amdgcn_s_barrier();
      asm volatile("s_waitcnt lgkmcnt(0)" ::: "memory");
      __builtin_amdgcn_s_setprio(1);
      #pragma unroll
      for (int mi = 4; mi < 8; ++mi)
        #pragma unroll
        for (int ni = 0; ni < 4; ++ni)
          acc[mi][ni] = __builtin_amdgcn_mfma_f32_16x16x32_bf16(a1[mi], b1[ni], acc[mi][ni], 0, 0, 0);
      __builtin_amdgcn_s_setprio(0);

      if (kt == 5) {
        // ---- col-tile epilogue: per-wave 64-col min -> redm, combine over wc
        #pragma unroll
        for (int mi = 0; mi < 8; ++mi) {
          #pragma unroll
          for (int r = 0; r < 4; ++r) {
            float tv = msq[0] - 2.f * acc[mi][0][r];
            #pragma unroll
            for (int ni = 1; ni < 4; ++ni) tv = fminf(tv, msq[ni] - 2.f * acc[mi][ni][r]);
            tv = fminf(tv, __shfl_xor(tv, 1));
            tv = fminf(tv, __shfl_xor(tv, 2));
            tv = fminf(tv, __shfl_xor(tv, 4));
            tv = fminf(tv, __shfl_xor(tv, 8));
            if ((lane & 15) == 0)
              redm[wc][wr * 128 + mi * 16 + ((lane >> 4) << 2) + r] = tv;
          }
          #pragma unroll
          for (int ni = 0; ni < 4; ++ni) acc[mi][ni] = (f32x4){0.f, 0.f, 0.f, 0.f};
        }
        __syncthreads();   // drains vmcnt+lgkm: redm visible AND next tile landed
        if (lane < 32) {
          const int rl = wid * 32 + lane;
          const float m01 = fminf(redm[0][rl], redm[1][rl]);
          const float m23 = fminf(redm[2][rl], redm[3][rl]);
          runmin = fminf(runmin, fminf(m01, m23));
        }
        if (c == W - 1 && lane < 32)
          partial[(size_t)blockIdx.x * MROWS + row0 + wid * 32 + lane] = runmin;
        // no extra barrier: next phase-1 has its own; redm reuse is 6 iters away
      } else {
        asm volatile("s_waitcnt vmcnt(0)" ::: "memory");    // next K-tile landed
        __builtin_amdgcn_s_barrier();
      }
    }
  }
}

// ---------------------------------------------------------------- finalize
// min over NCG group partials + x_sq (from bf16 A) + sqrt + per-image max.
__global__ __launch_bounds__(256) void finalize_kernel(
    const float* __restrict__ partial, const __hip_bfloat16* __restrict__ A,
    float* __restrict__ out)
{
  const int b = blockIdx.x;
  const int t = threadIdx.x;
  __shared__ float red[4];
  float lmax = 0.f;
  if (t < 196) {
    const int n0 = b * 784 + t * 4;
    float4 mn = {__uint_as_float(0x7f800000u), __uint_as_float(0x7f800000u),
                 __uint_as_float(0x7f800000u), __uint_as_float(0x7f800000u)};
    for (int g = 0; g < NCG; ++g) {
      const float4 p = *(const float4*)&partial[(size_t)g * MROWS + n0];
      mn.x = fminf(mn.x, p.x); mn.y = fminf(mn.y, p.y);
      mn.z = fminf(mn.z, p.z); mn.w = fminf(mn.w, p.w);
    }
    float xs[4];
    #pragma unroll
    for (int r = 0; r < 4; ++r) {
      const bf16x8* ap = (const bf16x8*)(A + (size_t)(n0 + r) * CTOT);
      float s = 0.f;
      for (int j = 0; j < 48; ++j) {
        const bf16x8 v = ap[j];
        #pragma unroll
        for (int e = 0; e < 8; ++e) {
          const float f = __uint_as_float(((unsigned)(unsigned short)v[e]) << 16);
          s += f * f;
        }
      }
      xs[r] = s;
    }
    float4 o;
    o.x = sqrtf(fmaxf(mn.x + xs[0], 1e-12f));
    o.y = sqrtf(fmaxf(mn.y + xs[1], 1e-12f));
    o.z = sqrtf(fmaxf(mn.z + xs[2], 1e-12f));
    o.w = sqrtf(fmaxf(mn.w + xs[3], 1e-12f));
    *(float4*)&out[n0] = o;
    lmax = fmaxf(fmaxf(o.x, o.y), fmaxf(o.z, o.w));
  }
  #pragma unroll
  for (int off = 32; off; off >>= 1) lmax = fmaxf(lmax, __shfl_xor(lmax, off));
  if ((t & 63) == 0) red[t >> 6] = lmax;
  __syncthreads();
  if (t == 0)
    out[6272 + b] = fmaxf(fmaxf(red[0], red[1]), fmaxf(red[2], red[3]));
}

// ---------------------------------------------------------------- launch
extern "C" void kernel_launch(void* const* d_in, const int* in_sizes, int n_in,
                              void* d_out, int out_size, void* d_ws, size_t ws_size,
                              hipStream_t stream)
{
  const float* f2 = (const float*)d_in[0];   // [8,128,28,28]
  const float* f3 = (const float*)d_in[1];   // [8,256,14,14]
  const float* mb = (const float*)d_in[2];   // [30000,384]
  float* out = (float*)d_out;                // 6272 patch scores + 8 img scores

  // workspace layout (16B-aligned), total ~28.9 MB
  uint8_t* ws = (uint8_t*)d_ws;
  __hip_bfloat16* A  = (__hip_bfloat16*)(ws);              // 6400*384*2   = 4,915,200
  __hip_bfloat16* Bb = (__hip_bfloat16*)(ws + 4915200);    // 30720*384*2  = 23,592,960
  float* m_sq   = (float*)(ws + 28508160);                 // 30720*4      =   122,880
  float* partial = (float*)(ws + 28631040);                // 10*6400*4    =   256,000

  hipLaunchKernelGGL(prep_kernel, dim3(NPREP), dim3(256), 0, stream,
                     f2, f3, mb, A, Bb, m_sq);
  hipLaunchKernelGGL(gemm_min_kernel, dim3(NCG, MROWS / 256), dim3(512), 0, stream,
                     A, Bb, m_sq, partial);
  hipLaunchKernelGGL(finalize_kernel, dim3(8), dim3(256), 0, stream,
                     partial, A, out);
}